// Round 2
// baseline (358.951 us; speedup 1.0000x reference)
//
#include <hip/hip_runtime.h>

#define D_   64
#define NBT_ 12800   // B*T = 32*400
#define B_   32

typedef float v2f __attribute__((ext_vector_type(2)));
typedef float v4f __attribute__((ext_vector_type(4)));

// Broadcast lane l's value of v to all lanes (SGPR result).
__device__ __forceinline__ float rl(float v, int l) {
    return __uint_as_float(__builtin_amdgcn_readlane(__float_as_uint(v), l));
}

// One wave (64 lanes) per (b,t) matrix. Lane i holds row i as 32 float2
// (64 VGPRs). Right-looking Cholesky, fully unrolled.
//
// Column broadcast goes through LDS instead of 2016 v_readlane ops:
//   - each lane writes its scaled col-k element: 1 ds_write_b32
//     (stride-1 across lanes -> 2 lanes/bank = conflict-free)
//   - all lanes read the column back in float4 chunks at a uniform
//     address -> hardware broadcast, conflict-free, on the LDS pipe
//     (overlaps the VALU FMA stream).
// Rank-1 trailing update is float2-packed (v_pk_fma_f32).
// Body shrinks ~4700 -> ~2400 instrs (~38 KB -> ~19 KB, fits 32 KB L1I).
//
// Partial leading chunks touch already-finalized columns with garbage;
// that garbage is confined to dead registers/lanes and never reaches a
// live diagonal, z, q or lg (all derived from broadcasts out of lanes
// that are still live at that iteration).
//
// Correctness note: same-iteration ds_write -> ds_read (cross-lane) relies
// on per-wave in-order DS execution; slots are double-buffered on k&1 so
// there is no cross-iteration WAR hazard.
__global__ __launch_bounds__(256, 4) void chol_ll(const float* __restrict__ x,
                                                  const float* __restrict__ mu,
                                                  const float* __restrict__ sigma,
                                                  float* __restrict__ partial) {
    const int lane = threadIdx.x & 63;
    const int wv   = threadIdx.x >> 6;
    const int bt   = blockIdx.x * 4 + wv;

    __shared__ __align__(16) float colbuf[4][2][D_];   // per-wave dbuf column
    float* const cb0 = colbuf[wv][0];
    float* const cb1 = colbuf[wv][1];

    const v4f* srow = (const v4f*)(sigma + (size_t)bt * (D_ * D_) + (size_t)lane * D_);
    v2f row[D_ / 2];
    #pragma unroll
    for (int m = 0; m < D_ / 4; ++m) {
        v4f t = srow[m];
        row[2 * m]     = (v2f){t[0], t[1]};
        row[2 * m + 1] = (v2f){t[2], t[3]};
    }
    float d = x[bt * D_ + lane] - mu[bt * D_ + lane];

    float q = 0.f, lg = 0.f;
    #pragma unroll
    for (int k = 0; k < D_; ++k) {
        // diagonal (lane k's element is valid) + EPS regularization
        float rk  = row[k >> 1][k & 1];
        float s   = rl(rk, k) + 1e-6f;
        float inv = __builtin_amdgcn_rsqf(s);   // 1/L[k][k]
        lg += __builtin_amdgcn_logf(s);         // log2(s); scaled at end
        float a = rk * inv;                     // L[i][k] for lanes i >= k
        // fused forward substitution: z_k = d_k / L[k][k]
        float zk = rl(d, k) * inv;
        q += zk * zk;
        d -= a * zk;                            // valid for lanes i > k

        if (k < D_ - 1) {
            // broadcast scaled column k via LDS (double-buffered slot)
            float* cb = (k & 1) ? cb1 : cb0;
            cb[lane] = a;
            // trailing rank-1 update in float4 column chunks.
            // chunk m covers columns 4m..4m+3; first chunk may update
            // dead columns (harmless, confined).
            const v2f av = {a, a};
            const int m0 = (k + 1) >> 2;
            #pragma unroll
            for (int m = m0; m < D_ / 4; ++m) {
                v4f bc = *(const v4f*)(cb + 4 * m);   // uniform-addr broadcast
                row[2 * m]     -= av * (v2f){bc[0], bc[1]};
                row[2 * m + 1] -= av * (v2f){bc[2], bc[3]};
            }
        }
    }

    if (lane == 0) {
        float log_det = 0.34657359027997264f * lg;      // 0.5 * ln(2) * sum(log2 s)
        // -0.5*sum(z^2) - log_det - 0.5*D*ln(2*pi)
        float lp = -0.5f * q - log_det - 58.81206612509905f;
        partial[bt] = lp;
    }
}

__global__ __launch_bounds__(1024) void reduce_ll(const float* __restrict__ partial,
                                                  float* __restrict__ out) {
    float s = 0.f;
    for (int i = threadIdx.x; i < NBT_; i += 1024) s += partial[i];
    #pragma unroll
    for (int off = 32; off > 0; off >>= 1) s += __shfl_down(s, off, 64);
    __shared__ float ws[16];
    const int lane = threadIdx.x & 63, w = threadIdx.x >> 6;
    if (lane == 0) ws[w] = s;
    __syncthreads();
    if (threadIdx.x == 0) {
        float t = 0.f;
        #pragma unroll
        for (int i = 0; i < 16; ++i) t += ws[i];
        out[0] = -t / (float)B_;   // out = -mean_b sum_t log_prob
    }
}

extern "C" void kernel_launch(void* const* d_in, const int* in_sizes, int n_in,
                              void* d_out, int out_size, void* d_ws, size_t ws_size,
                              hipStream_t stream) {
    const float* x     = (const float*)d_in[0];
    const float* mu    = (const float*)d_in[1];
    const float* sigma = (const float*)d_in[2];
    float* partial = (float*)d_ws;   // NBT_ floats = 51.2 KB scratch
    chol_ll<<<NBT_ / 4, 256, 0, stream>>>(x, mu, sigma, partial);
    reduce_ll<<<1, 1024, 0, stream>>>(partial, (float*)d_out);
}

// Round 3
// 318.555 us; speedup vs baseline: 1.1268x; 1.1268x over previous
//
#include <hip/hip_runtime.h>

#define D_   64
#define NBT_ 12800   // B*T = 32*400
#define B_   32

typedef float v4f __attribute__((ext_vector_type(4)));

// Broadcast lane l's value of v to all lanes (SGPR result).
__device__ __forceinline__ float rl(float v, int l) {
    return __uint_as_float(__builtin_amdgcn_readlane(__float_as_uint(v), l));
}

// One wave (64 lanes) per (b,t) matrix. Lane i holds row i of sigma as a
// plain float[64] (register-resident — round 0 measured 84 VGPRs with this
// exact layout; ext-vector row arrays spilled to scratch in round 2:
// VGPR=64, WRITE_SIZE=121 MB).
//
// Column broadcast goes through LDS instead of per-element v_readlane:
//   - each lane writes its scaled col-k element: 1 ds_write_b32
//     (stride-1 across lanes -> 2 lanes/bank = free)
//   - all lanes read the column back in v4f chunks at a UNIFORM address ->
//     hardware broadcast, conflict-free (round 2: SQ_LDS_BANK_CONFLICT=0),
//     on the LDS pipe, overlapping the VALU FMA stream.
// Same-iteration ds_write -> ds_read cross-lane visibility relies on
// per-wave in-order DS execution — validated on HW by round 2 (passed,
// absmax 0.0).
//
// First v4f chunk of each trailing update may touch already-finalized
// columns (j <= k) with garbage; those registers are dead (never read
// after their own iteration: the diagonal, z, q, lg are all consumed
// before the update runs). Keeps the per-k code uniform.
__global__ __launch_bounds__(256) void chol_ll(const float* __restrict__ x,
                                               const float* __restrict__ mu,
                                               const float* __restrict__ sigma,
                                               float* __restrict__ partial) {
    const int lane = threadIdx.x & 63;
    const int wv   = threadIdx.x >> 6;
    const int bt   = blockIdx.x * 4 + wv;

    __shared__ __align__(16) float colbuf[4][2][D_];   // per-wave dbuf column
    float* const cb0 = colbuf[wv][0];
    float* const cb1 = colbuf[wv][1];

    const float4* srow = (const float4*)(sigma + (size_t)bt * (D_ * D_) + (size_t)lane * D_);
    float row[D_];
    #pragma unroll
    for (int m = 0; m < D_ / 4; ++m) {
        float4 t = srow[m];
        row[4 * m + 0] = t.x; row[4 * m + 1] = t.y;
        row[4 * m + 2] = t.z; row[4 * m + 3] = t.w;
    }
    float d = x[bt * D_ + lane] - mu[bt * D_ + lane];

    float q = 0.f, lg = 0.f;
    #pragma unroll
    for (int k = 0; k < D_; ++k) {
        // diagonal (lane k's row[k] is valid) + EPS regularization
        float s   = rl(row[k], k) + 1e-6f;
        float inv = __builtin_amdgcn_rsqf(s);   // 1/L[k][k]
        lg += __builtin_amdgcn_logf(s);         // log2(s); scaled at end
        float a = row[k] * inv;                 // L[i][k] for lanes i >= k
        // fused forward substitution: z_k = d_k / L[k][k]
        float zk = rl(d, k) * inv;
        q += zk * zk;
        d -= a * zk;                            // valid for lanes i > k

        if (k < D_ - 1) {
            // broadcast scaled column k via LDS (double-buffered slot)
            float* cb = (k & 1) ? cb1 : cb0;
            cb[lane] = a;
            // trailing rank-1 update in v4f column chunks; chunk m covers
            // columns 4m..4m+3. First chunk may hit dead columns (harmless).
            const int m0 = (k + 1) >> 2;
            #pragma unroll
            for (int m = m0; m < D_ / 4; ++m) {
                v4f bc = *(const v4f*)(cb + 4 * m);   // uniform-addr broadcast
                row[4 * m + 0] -= a * bc[0];
                row[4 * m + 1] -= a * bc[1];
                row[4 * m + 2] -= a * bc[2];
                row[4 * m + 3] -= a * bc[3];
            }
        }
    }

    if (lane == 0) {
        float log_det = 0.34657359027997264f * lg;      // 0.5 * ln(2) * sum(log2 s)
        // -0.5*sum(z^2) - log_det - 0.5*D*ln(2*pi)
        float lp = -0.5f * q - log_det - 58.81206612509905f;
        partial[bt] = lp;
    }
}

__global__ __launch_bounds__(1024) void reduce_ll(const float* __restrict__ partial,
                                                  float* __restrict__ out) {
    float s = 0.f;
    for (int i = threadIdx.x; i < NBT_; i += 1024) s += partial[i];
    #pragma unroll
    for (int off = 32; off > 0; off >>= 1) s += __shfl_down(s, off, 64);
    __shared__ float ws[16];
    const int lane = threadIdx.x & 63, w = threadIdx.x >> 6;
    if (lane == 0) ws[w] = s;
    __syncthreads();
    if (threadIdx.x == 0) {
        float t = 0.f;
        #pragma unroll
        for (int i = 0; i < 16; ++i) t += ws[i];
        out[0] = -t / (float)B_;   // out = -mean_b sum_t log_prob
    }
}

extern "C" void kernel_launch(void* const* d_in, const int* in_sizes, int n_in,
                              void* d_out, int out_size, void* d_ws, size_t ws_size,
                              hipStream_t stream) {
    const float* x     = (const float*)d_in[0];
    const float* mu    = (const float*)d_in[1];
    const float* sigma = (const float*)d_in[2];
    float* partial = (float*)d_ws;   // NBT_ floats = 51.2 KB scratch
    chol_ll<<<NBT_ / 4, 256, 0, stream>>>(x, mu, sigma, partial);
    reduce_ll<<<1, 1024, 0, stream>>>(partial, (float*)d_out);
}